// Round 4
// baseline (241.261 us; speedup 1.0000x reference)
//
#include <hip/hip_runtime.h>

#define W 320
#define H 96
#define FS 96
#define BS 8
#define NPLANES 9      // 1 + 2*4 levels
#define CH 16          // channels staged per LDS stage
#define NSTAGES 6      // FS / CH
#define CW 160         // columns per block (W/2) -> 2 chunks per row
#define HALO 4
#define SROW 168       // HALO + CW + HALO floats per channel (42 float4 quads)
#define QPC 42         // quads per channel row
#define NTHREADS 128   // 2 waves; 80 active in compute (VX=2 over CW=160)

__global__ __launch_bounds__(NTHREADS, 3)
void cost_volume_kernel(const float* __restrict__ f1,
                        const float* __restrict__ f2,
                        float* __restrict__ out)
{
    __shared__ __align__(16) float sh[CH * SROW];   // 10,752 B

    const int t     = threadIdx.x;
    const int idx   = blockIdx.x;
    const int chunk = idx & 1;            // 0 | 1  -> xb = 0 | 160
    const int row   = idx >> 1;           // 0..767 = (b, y)
    const int b     = row / H;
    const int y     = row % H;
    const int xb    = chunk * CW;

    const size_t rowoff = ((size_t)(b * FS) * H + y) * W;
    const float* f1row = f1 + rowoff;     // + c*H*W per channel
    const float* f2row = f2 + rowoff;

    // staging map: thread owns channel sc = t>>3, sub-lane su = t&7,
    // quads q = su + 8k, k=0..5 (q<42). Quad q covers global cols xb-4+4q..+3.
    const int sc = t >> 3;
    const int su = t & 7;

    // per-k column offsets + validity (uniform per thread, hoisted out of loop)
    int  koff[6];
    bool kval[6];
#pragma unroll
    for (int k = 0; k < 6; ++k) {
        const int q   = su + 8 * k;
        const int col = xb - HALO + 4 * q;        // multiple of 4
        koff[k] = col;
        kval[k] = (q < QPC) && ((unsigned)col < W);
    }

    float4 r[6];
#pragma unroll
    for (int k = 0; k < 6; ++k) r[k] = make_float4(0.f, 0.f, 0.f, 0.f);

    const int xi = t;          // compute lane: xi < 80
    const int x0 = 2 * xi;     // local column, even -> 8B-aligned reads
    const bool active = (xi < 80);

    auto issueF2 = [&](int c0) {
        const float* f2c = f2row + (size_t)(c0 + sc) * (H * W);
#pragma unroll
        for (int k = 0; k < 6; ++k)
            if (kval[k]) r[k] = *(const float4*)(f2c + koff[k]);
    };

    auto writeF2 = [&]() {
#pragma unroll
        for (int k = 0; k < 6; ++k) {
            const int q = su + 8 * k;
            if (q < QPC)
                *(float4*)(&sh[sc * SROW + 4 * q]) = r[k];
        }
    };

    auto loadA = [&](int c0, float2* a) {
        if (active) {
#pragma unroll
            for (int c = 0; c < CH; ++c)
                a[c] = *(const float2*)(f1row + (size_t)(c0 + c) * (H * W) + xb + x0);
        }
    };

    float acc0[NPLANES], acc1[NPLANES];
#pragma unroll
    for (int p = 0; p < NPLANES; ++p) { acc0[p] = 0.f; acc1[p] = 0.f; }

    auto compute = [&](const float2* a) {
        if (active) {
#pragma unroll
            for (int c = 0; c < CH; ++c) {
                // wv[j] = f2[xb + x0 - 4 + j], j=0..9 (halo-padded via staging)
                float wv[10];
#pragma unroll
                for (int k = 0; k < 5; ++k) {
                    const float2 v = *(const float2*)(&sh[c * SROW + x0 + 2 * k]);
                    wv[2 * k]     = v.x;
                    wv[2 * k + 1] = v.y;
                }
                // plane p <-> shift i = p-4; f2 col = x - i = x + 4 - p
#pragma unroll
                for (int p = 0; p < NPLANES; ++p) {
                    acc0[p] = fmaf(a[c].x, wv[8 - p], acc0[p]);
                    acc1[p] = fmaf(a[c].y, wv[9 - p], acc1[p]);
                }
            }
        }
    };

    // prologue: stage-0 f2 and f1 loads in flight before first barrier
    issueF2(0);
    float2 aA[CH], aB[CH];
    loadA(0, aA);

    // Fully unrolled stage loop: ping-pong f1 reg buffers statically indexed.
    // Per stage: B1 (drains last stage's prefetches, all landed during compute)
    //   -> LDS write -> B2 -> issue next-stage f2+f1 (fly across compute)
    //   -> compute from regs+LDS (no global waits inside).
#pragma unroll
    for (int s = 0; s < NSTAGES; ++s) {
        __syncthreads();                 // B1
        writeF2();
        __syncthreads();                 // B2
        if (s + 1 < NSTAGES) {
            issueF2((s + 1) * CH);
            loadA((s + 1) * CH, (s & 1) ? aA : aB);
        }
        compute((s & 1) ? aB : aA);
    }

    if (active) {
        const float scale = 1.0f / (float)FS;
#pragma unroll
        for (int p = 0; p < NPLANES; ++p) {
            float2 o;
            o.x = acc0[p] * scale;
            o.y = acc1[p] * scale;
            *(float2*)(out + (((size_t)(b * NPLANES + p)) * H + y) * W + xb + x0) = o;
        }
    }
}

extern "C" void kernel_launch(void* const* d_in, const int* in_sizes, int n_in,
                              void* d_out, int out_size, void* d_ws, size_t ws_size,
                              hipStream_t stream) {
    (void)in_sizes; (void)n_in; (void)d_ws; (void)ws_size; (void)out_size;
    const float* f1 = (const float*)d_in[0];
    const float* f2 = (const float*)d_in[1];
    float* out = (float*)d_out;

    dim3 grid(BS * H * 2);    // 1536 blocks = 6 per CU
    dim3 block(NTHREADS);
    cost_volume_kernel<<<grid, block, 0, stream>>>(f1, f2, out);
}

// Round 6
// 213.283 us; speedup vs baseline: 1.1312x; 1.1312x over previous
//
#include <hip/hip_runtime.h>

#define W 320
#define H 96
#define FS 96
#define BS 8
#define NPLANES 9      // 1 + 2*4 levels
#define CH 16          // channels staged per LDS stage
#define NSTAGES 6      // FS / CH
#define CW 160         // columns per block (W/2) -> 2 chunks per row
#define HALO 4
#define SROW 168       // HALO + CW + HALO floats per channel (42 float4 quads)
#define QPC 42         // quads per channel row
#define NTHREADS 128   // 2 waves; 80 active in compute (VX=2 over CW=160)

__global__ __launch_bounds__(NTHREADS, 3)
void cost_volume_kernel(const float* __restrict__ f1,
                        const float* __restrict__ f2,
                        float* __restrict__ out)
{
    __shared__ __align__(16) float sh[CH * SROW];   // 10,752 B

    const int t     = threadIdx.x;
    const int idx   = blockIdx.x;
    const int chunk = idx & 1;            // 0 | 1  -> xb = 0 | 160
    const int row   = idx >> 1;           // 0..767 = (b, y)
    const int b     = row / H;
    const int y     = row % H;
    const int xb    = chunk * CW;

    const size_t rowoff = ((size_t)(b * FS) * H + y) * W;
    const float* f1row = f1 + rowoff;     // + c*H*W per channel
    const float* f2row = f2 + rowoff;

    // staging map: thread owns channel sc = t>>3, sub-lane su = t&7,
    // quads q = su + 8k, k=0..5 (q<42). Quad q covers global cols xb-4+4q..+3.
    const int sc = t >> 3;
    const int su = t & 7;

    int  koff[6];
    bool kval[6];
#pragma unroll
    for (int k = 0; k < 6; ++k) {
        const int q   = su + 8 * k;
        const int col = xb - HALO + 4 * q;        // multiple of 4
        koff[k] = col;
        kval[k] = (q < QPC) && ((unsigned)col < W);
    }

    float4 r[6];
#pragma unroll
    for (int k = 0; k < 6; ++k) r[k] = make_float4(0.f, 0.f, 0.f, 0.f);

    const int xi = t;          // compute lane: xi < 80
    const int x0 = 2 * xi;     // local column, even -> 8B-aligned reads
    const bool active = (xi < 80);

    float acc0[NPLANES], acc1[NPLANES];
#pragma unroll
    for (int p = 0; p < NPLANES; ++p) { acc0[p] = 0.f; acc1[p] = 0.f; }

    // f1 ping-pong register buffers. CRITICAL: only ever accessed by literal
    // name through the macros below — no pointer/reference parameters, no
    // runtime selection. Round-4 post-mortem: a `(s&1)?aA:aB` pointer select
    // through a lambda param sent these to scratch (WRITE_SIZE 8.6->90 MB).
    float2 aA[CH], aB[CH];

#define ISSUE_F2(c0_) do {                                                   \
    const float* f2c_ = f2row + (size_t)((c0_) + sc) * (H * W);              \
    _Pragma("unroll")                                                        \
    for (int k = 0; k < 6; ++k)                                              \
        if (kval[k]) r[k] = *(const float4*)(f2c_ + koff[k]);                \
} while (0)

#define WRITE_F2() do {                                                      \
    _Pragma("unroll")                                                        \
    for (int k = 0; k < 6; ++k) {                                            \
        const int q_ = su + 8 * k;                                           \
        if (q_ < QPC) *(float4*)(&sh[sc * SROW + 4 * q_]) = r[k];            \
    }                                                                        \
} while (0)

#define LOAD_A(c0_, A_) do {                                                 \
    if (active) {                                                            \
        _Pragma("unroll")                                                    \
        for (int c = 0; c < CH; ++c)                                         \
            A_[c] = *(const float2*)(f1row + (size_t)((c0_) + c) * (H * W)   \
                                     + xb + x0);                             \
    }                                                                        \
} while (0)

#define COMPUTE(A_) do {                                                     \
    if (active) {                                                            \
        _Pragma("unroll")                                                    \
        for (int c = 0; c < CH; ++c) {                                       \
            /* wv[j] = f2[xb+x0-4+j], j=0..9 (halo-padded via staging) */    \
            float wv[10];                                                    \
            _Pragma("unroll")                                                \
            for (int k = 0; k < 5; ++k) {                                    \
                const float2 v_ = *(const float2*)(&sh[c * SROW + x0 + 2*k]);\
                wv[2 * k]     = v_.x;                                        \
                wv[2 * k + 1] = v_.y;                                        \
            }                                                                \
            /* plane p <-> shift i = p-4; f2 col = x - i = x + 4 - p */      \
            _Pragma("unroll")                                                \
            for (int p = 0; p < NPLANES; ++p) {                              \
                acc0[p] = fmaf(A_[c].x, wv[8 - p], acc0[p]);                 \
                acc1[p] = fmaf(A_[c].y, wv[9 - p], acc1[p]);                 \
            }                                                                \
        }                                                                    \
    }                                                                        \
} while (0)

    // prologue: stage-0 f2 + f1 loads in flight before first barrier
    ISSUE_F2(0);
    LOAD_A(0, aA);

    // Hand-unrolled pipeline. Per stage: B1 (drains prefetches that flew
    // across the previous compute) -> LDS write -> B2 -> issue next-stage
    // f2+f1 -> compute current stage from regs+LDS (no global waits inside).
    // s=0
    __syncthreads(); WRITE_F2(); __syncthreads();
    ISSUE_F2(1 * CH); LOAD_A(1 * CH, aB);
    COMPUTE(aA);
    // s=1
    __syncthreads(); WRITE_F2(); __syncthreads();
    ISSUE_F2(2 * CH); LOAD_A(2 * CH, aA);
    COMPUTE(aB);
    // s=2
    __syncthreads(); WRITE_F2(); __syncthreads();
    ISSUE_F2(3 * CH); LOAD_A(3 * CH, aB);
    COMPUTE(aA);
    // s=3
    __syncthreads(); WRITE_F2(); __syncthreads();
    ISSUE_F2(4 * CH); LOAD_A(4 * CH, aA);
    COMPUTE(aB);
    // s=4
    __syncthreads(); WRITE_F2(); __syncthreads();
    ISSUE_F2(5 * CH); LOAD_A(5 * CH, aB);
    COMPUTE(aA);
    // s=5 (no prefetch)
    __syncthreads(); WRITE_F2(); __syncthreads();
    COMPUTE(aB);

#undef ISSUE_F2
#undef WRITE_F2
#undef LOAD_A
#undef COMPUTE

    if (active) {
        const float scale = 1.0f / (float)FS;
#pragma unroll
        for (int p = 0; p < NPLANES; ++p) {
            float2 o;
            o.x = acc0[p] * scale;
            o.y = acc1[p] * scale;
            *(float2*)(out + (((size_t)(b * NPLANES + p)) * H + y) * W + xb + x0) = o;
        }
    }
}

extern "C" void kernel_launch(void* const* d_in, const int* in_sizes, int n_in,
                              void* d_out, int out_size, void* d_ws, size_t ws_size,
                              hipStream_t stream) {
    (void)in_sizes; (void)n_in; (void)d_ws; (void)ws_size; (void)out_size;
    const float* f1 = (const float*)d_in[0];
    const float* f2 = (const float*)d_in[1];
    float* out = (float*)d_out;

    dim3 grid(BS * H * 2);    // 1536 blocks = 6 per CU
    dim3 block(NTHREADS);
    cost_volume_kernel<<<grid, block, 0, stream>>>(f1, f2, out);
}

// Round 7
// 208.751 us; speedup vs baseline: 1.1557x; 1.0217x over previous
//
#include <hip/hip_runtime.h>

#define W 320
#define H 96
#define FS 96
#define BS 8
#define NPLANES 9
#define CPW 24            // channels per wave (FS / 4 waves)
#define NTHREADS 256      // 4 waves per block, one (b,y) row per block
#define RSTRIDE 52        // LDS floats per lane slot (45 used, padded, 16B-aligned)

// 4-byte-aligned float4: x0 = 5*lane is only dword-aligned
typedef float f4 __attribute__((ext_vector_type(4), aligned(4)));

__global__ __launch_bounds__(NTHREADS, 3)
void cost_volume_kernel(const float* __restrict__ f1,
                        const float* __restrict__ f2,
                        float* __restrict__ out)
{
    // end-reduction buffer only: waves 1..3 park 45 partials/lane
    __shared__ float red[3 * 64 * RSTRIDE];   // 39,936 B -> 3 blocks/CU

    const int t   = threadIdx.x;
    const int wv  = t >> 6;          // wave 0..3
    const int l   = t & 63;          // lane
    const int row = blockIdx.x;      // 0..767 = (b, y)
    const int b   = row / H;
    const int y   = row % H;

    // lane covers output cols x0..x0+4 (VX=5; 64*5 = 320 exactly)
    const int x0 = 5 * l;
    // f2 window needed: cols x0-4 .. x0+12 (planes shift +-4), loaded as
    // 3 quads + 1 scalar with edge-clamped addresses; clamped lanes' values
    // are zeroed by bitmask (AND, not mul: clamped reads may be Inf/NaN).
    const int o0 = (x0 - 4 < 0)   ? 0   : x0 - 4;   // quad: e0..e3
    const int o2 = (x0 + 4 > 316) ? 316 : x0 + 4;   // quad: e8..e11
    const int o3 = (x0 + 8 > 319) ? 319 : x0 + 8;   // scalar: e12
    const unsigned mlo = (l == 0)  ? 0u : ~0u;  // lane 0: cols -4..-1 invalid
    const unsigned mhi = (l == 63) ? 0u : ~0u;  // lane 63: cols 320..323 invalid
    const bool hi = (l == 63);                  // lane 63: e8 (col 319) = q2.w

    const size_t rowoff = ((size_t)(b * FS) * H + y) * W;
    const float* f1w = f1 + rowoff + (size_t)(wv * CPW) * (H * W);
    const float* f2w = f2 + rowoff + (size_t)(wv * CPW) * (H * W);

    float acc[5][9];
#pragma unroll
    for (int j = 0; j < 5; ++j)
#pragma unroll
        for (int p = 0; p < 9; ++p) acc[j][p] = 0.f;

    // ---- streaming channel loop: no LDS, no barriers, pure load->FMA ----
#pragma unroll 6
    for (int cc = 0; cc < CPW; ++cc) {
        const float* f1c = f1w + (size_t)cc * (H * W);
        const float* f2c = f2w + (size_t)cc * (H * W);

        const f4   q0 = *(const f4*)(f2c + o0);
        const f4   q1 = *(const f4*)(f2c + x0);      // e4..e7, always valid
        const f4   q2 = *(const f4*)(f2c + o2);
        const float s3 = f2c[o3];
        const f4   af = *(const f4*)(f1c + x0);      // a0..a3, always valid
        const float a4 = f1c[x0 + 4];                // x0+4 <= 319

        float w_[13];
        w_[0]  = __uint_as_float(__float_as_uint(q0.x) & mlo);
        w_[1]  = __uint_as_float(__float_as_uint(q0.y) & mlo);
        w_[2]  = __uint_as_float(__float_as_uint(q0.z) & mlo);
        w_[3]  = __uint_as_float(__float_as_uint(q0.w) & mlo);
        w_[4]  = q1.x;  w_[5] = q1.y;  w_[6] = q1.z;  w_[7] = q1.w;
        w_[8]  = hi ? q2.w : q2.x;   // lane63's q2 clamped to 316 -> col319=.w
        w_[9]  = __uint_as_float(__float_as_uint(q2.y) & mhi);
        w_[10] = __uint_as_float(__float_as_uint(q2.z) & mhi);
        w_[11] = __uint_as_float(__float_as_uint(q2.w) & mhi);
        w_[12] = __uint_as_float(__float_as_uint(s3)   & mhi);

        const float a_[5] = { af.x, af.y, af.z, af.w, a4 };

        // plane p <-> shift i = p-4; f2 col = x - i = x0 + j + 4 - p
        // window index e = col - (x0-4) = j + 8 - p  (0..12)
#pragma unroll
        for (int j = 0; j < 5; ++j)
#pragma unroll
            for (int p = 0; p < 9; ++p)
                acc[j][p] = fmaf(a_[j], w_[j + 8 - p], acc[j][p]);
    }

    // ---- single end-of-kernel combine: waves 1..3 -> LDS, wave 0 sums ----
    if (wv != 0) {
        float* dst = &red[((wv - 1) * 64 + l) * RSTRIDE];
#pragma unroll
        for (int j = 0; j < 5; ++j)
#pragma unroll
            for (int p = 0; p < 9; ++p)
                dst[j * 9 + p] = acc[j][p];
    }
    __syncthreads();
    if (wv == 0) {
#pragma unroll
        for (int u = 0; u < 3; ++u) {
            const float* src = &red[(u * 64 + l) * RSTRIDE];
#pragma unroll
            for (int j = 0; j < 5; ++j)
#pragma unroll
                for (int p = 0; p < 9; ++p)
                    acc[j][p] += src[j * 9 + p];
        }
        const float scale = 1.0f / (float)FS;
#pragma unroll
        for (int p = 0; p < 9; ++p) {
            float* op = out + (((size_t)(b * NPLANES + p)) * H + y) * W + x0;
            f4 v;
            v.x = acc[0][p] * scale;
            v.y = acc[1][p] * scale;
            v.z = acc[2][p] * scale;
            v.w = acc[3][p] * scale;
            *(f4*)op = v;
            op[4] = acc[4][p] * scale;
        }
    }
}

extern "C" void kernel_launch(void* const* d_in, const int* in_sizes, int n_in,
                              void* d_out, int out_size, void* d_ws, size_t ws_size,
                              hipStream_t stream) {
    (void)in_sizes; (void)n_in; (void)d_ws; (void)ws_size; (void)out_size;
    const float* f1 = (const float*)d_in[0];
    const float* f2 = (const float*)d_in[1];
    float* out = (float*)d_out;

    dim3 grid(BS * H);        // 768 blocks x 4 waves = 12 waves/CU
    dim3 block(NTHREADS);
    cost_volume_kernel<<<grid, block, 0, stream>>>(f1, f2, out);
}